// Round 7
// baseline (117.590 us; speedup 1.0000x reference)
//
#include <hip/hip_runtime.h>
#include <stdint.h>

// DiscreteMarkovDynamics: 5-step Markov jump sim, B=32, L=4096, V=512.
// R1: table precompute + wave-per-position categorical -> 1024 us.
// R2: provable-reject skip (u >= pthr[s] => categorical dead code) -> 250 us.
// R3: split/parallel builds, LDS pthr, PPW=8 -> 125 us.
// R4: fused wide build; ballot candidate scan -> 121 us (markov 52).
// R5: zoned work-steal REGRESSED (atomics on one cacheline) -> 293 us. Reverted.
// R6: 2-wave blocks + ILP categorical -> 116 us (markov 45, Occ 27% = churn).
// R7: (a) markov: 8192 persistent waves (exact residency, zero churn), 2 static
//     chunks/wave; pthr once per position + shfl; argmax butterfly carries the
//     winner's row value (kills the dependent rate load). (b) build: both
//     phases load-batched (16-wide register batches) with unchanged fp64
//     accumulation order -> latency hidden, bits identical.

#define VOCAB  512
#define EMB    256
#define HID    64
#define NPOS   (32 * 4096)   // B*L = 131072
#define STEPS  5
#define PPW    8             // positions per chunk; PPW*STEPS=40 <= 64 lanes
#define CHUNKS (NPOS / PPW)  // 16384
#define NWAVE  8192          // persistent waves; 2 chunks each

// Exact mirror of jax._src.prng.threefry2x32 (20 rounds).
__host__ __device__ __forceinline__ void tf2x32(uint32_t k0, uint32_t k1,
                                                uint32_t x0, uint32_t x1,
                                                uint32_t& o0, uint32_t& o1) {
  uint32_t ks2 = k0 ^ k1 ^ 0x1BD11BDAu;
  x0 += k0; x1 += k1;
#define TFR(r) { x0 += x1; x1 = (x1 << (r)) | (x1 >> (32 - (r))); x1 ^= x0; }
  TFR(13) TFR(15) TFR(26) TFR(6)
  x0 += k1;  x1 += ks2 + 1u;
  TFR(17) TFR(29) TFR(16) TFR(24)
  x0 += ks2; x1 += k0 + 2u;
  TFR(13) TFR(15) TFR(26) TFR(6)
  x0 += k0;  x1 += k1 + 3u;
  TFR(17) TFR(29) TFR(16) TFR(24)
  x0 += k1;  x1 += ks2 + 4u;
  TFR(13) TFR(15) TFR(26) TFR(6)
  x0 += ks2; x1 += k0 + 5u;
#undef TFR
  o0 = x0; o1 = x1;
}

struct Keys {
  uint32_t k1a[STEPS], k1b[STEPS];  // categorical (gumbel) keys per step
  uint32_t k2a[STEPS], k2b[STEPS];  // accept-uniform keys per step
};

// Fused table build: one block per state s, 512 threads. Load-batched (16-wide
// register batches keep 16 L2 loads in flight), fp64 accumulation ORDER
// unchanged from R4-R6 (bitwise-identical results).
__global__ __launch_bounds__(512)
void build_table(const float* __restrict__ emb,
                 const float* __restrict__ W1,
                 const float* __restrict__ b1,
                 const float* __restrict__ W2,
                 const float* __restrict__ b2,
                 float* __restrict__ I,
                 float* __restrict__ pthr) {
  const int s   = blockIdx.x;
  const int tid = threadIdx.x;
  __shared__ double part[8][HID];
  __shared__ double hd[HID];
  __shared__ float  redmax[8];

  const int hid = tid & (HID - 1);
  const int kq  = tid >> 6;               // 0..7, k = kq + 8*i
  const float* e = emb + s * EMB;
  double acc = 0.0;
#pragma unroll
  for (int ib = 0; ib < 32; ib += 16) {   // two 16-wide batches
    float ev[16], wv[16];
#pragma unroll
    for (int i = 0; i < 16; ++i) {        // 32 loads issued together
      const int k = kq + 8 * (ib + i);
      ev[i] = e[k];
      wv[i] = W1[k * HID + hid];
    }
#pragma unroll
    for (int i = 0; i < 16; ++i)          // same order as R4's k-loop
      acc += (double)ev[i] * (double)wv[i];
  }
  part[kq][hid] = acc;
  __syncthreads();
  if (kq == 0) {
    const double a = ((part[0][hid] + part[1][hid]) + (part[2][hid] + part[3][hid]))
                   + ((part[4][hid] + part[5][hid]) + (part[6][hid] + part[7][hid]));
    const float m = (float)a + b1[hid];
    hd[hid] = (double)(m > 0.0f ? m : 0.0f);   // relu
  }
  __syncthreads();

  double acc2 = 0.0;
#pragma unroll
  for (int kb = 0; kb < HID; kb += 16) {  // four 16-wide batches
    float wv[16];
#pragma unroll
    for (int i = 0; i < 16; ++i)
      wv[i] = W2[(kb + i) * VOCAB + tid]; // coalesced, 16 in flight
#pragma unroll
    for (int i = 0; i < 16; ++i)          // same serial order as before
      acc2 += hd[kb + i] * (double)wv[i];
  }
  const float val = (float)acc2 + b2[tid];
  I[s * VOCAB + tid] = val;

  float lmax = val;                        // max is order-insensitive
  for (int off = 32; off > 0; off >>= 1)
    lmax = fmaxf(lmax, __shfl_xor(lmax, off, 64));
  if ((tid & 63) == 0) redmax[tid >> 6] = lmax;
  __syncthreads();
  if (tid == 0) {
    float m = redmax[0];
#pragma unroll
    for (int i = 1; i < 8; ++i) m = fmaxf(m, redmax[i]);
    const float z = (-m) * 0.01f;          // same chain as accept path
    pthr[s] = 1.0f - (float)exp((double)z);// monotone => safe reject bound
  }
}

// Markov kernel: 8192 persistent waves (2048 blocks x 256 = exact full
// residency, zero churn), each wave statically owns chunks wid and wid+8192.
// Per chunk: one ballot finds all candidate (p,t); loop only over set bits.
__global__ __launch_bounds__(256)
void markov_kernel(const int* __restrict__ x_in,
                   const float* __restrict__ I,
                   const float* __restrict__ pthr,
                   int* __restrict__ x_out,
                   Keys K) {
  const int lane = threadIdx.x & 63;
  const int wid  = (blockIdx.x << 2) | (threadIdx.x >> 6);  // 0..8191
  const int qp = lane / 5;                 // lane q -> (position, step)
  const int qt = lane - qp * 5;
  const float TINYF = 1.17549435e-38f;

#pragma unroll
  for (int c = 0; c < 2; ++c) {
    const int base = (wid + (c << 13)) * PPW;

    // States (lanes 0..7), then per-position pthr, shfl'd to the test lanes.
    int scur = (lane < PPW) ? x_in[base + lane] : 0;
    const float pv = (lane < PPW) ? pthr[scur] : 0.0f;

    // Accept uniforms: lane q < 40 holds u for (p=q/5, t=q%5).
    float u40 = 0.0f;
    if (lane < PPW * STEPS) {
      uint32_t w0, w1;
      tf2x32(K.k2a[qt], K.k2b[qt], 0u, (uint32_t)(base + qp), w0, w1);
      u40 = __uint_as_float((((w0 ^ w1) >> 9) | 0x3f800000u)) - 1.0f;
    }

    // Candidate mask: u_q < pthr[s_p] (state fixed unless an accept occurs).
    const float pq = __shfl(pv, qp, 64);
    const bool cand = (lane < PPW * STEPS) && (u40 < pq);
    unsigned long long mask = __ballot(cand);

    while (mask) {
      const int q = (int)__builtin_ctzll(mask);   // wave-uniform
      mask &= mask - 1;
      const int p = q / 5;
      const int t = q - p * 5;
      const int s = __builtin_amdgcn_readfirstlane(__shfl(scur, p, 64));

      // --- Full categorical (bit-identical math; ILP-batched) ---
      const float* row = I + s * VOCAB;
      float rv[8];
#pragma unroll
      for (int j = 0; j < 8; ++j)               // prefetch row values (L2)
        rv[j] = row[lane + (j << 6)];

      const uint32_t fbase = ((uint32_t)(base + p) << 9) + (uint32_t)lane;
      uint32_t bits[8];
#pragma unroll
      for (int j = 0; j < 8; ++j) {             // 8 independent threefry
        uint32_t w0, w1;
        tf2x32(K.k1a[t], K.k1b[t], 0u, fbase + ((uint32_t)j << 6), w0, w1);
        bits[j] = w0 ^ w1;
      }

      float best = -__builtin_inff();
      float rbest = 0.0f;                        // row value of the winner
      int bidx = 0;
#pragma unroll
      for (int j = 0; j < 8; ++j) {             // 8 independent gumbel chains
        float ufv = __uint_as_float((bits[j] >> 9) | 0x3f800000u) - 1.0f;
        if (ufv == 0.0f) ufv = TINYF;
        const float g = -logf(-logf(ufv));
        const int v = lane + (j << 6);
        if (v != s) {
          const float val = rv[j] + g;
          if (val > best) { best = val; bidx = v; rbest = rv[j]; }
        }
      }
      for (int off = 32; off > 0; off >>= 1) {
        const float ob = __shfl_xor(best, off, 64);
        const int   oi = __shfl_xor(bidx, off, 64);
        const float orv = __shfl_xor(rbest, off, 64);
        if (ob > best || (ob == best && oi < bidx)) {
          best = ob; bidx = oi; rbest = orv;
        }
      }
      bidx = __builtin_amdgcn_readfirstlane(bidx);
      const float rate = rbest;                 // == row[bidx], no L2 load
      const float z = (-rate) * 0.01f;
      const float pacc = 1.0f - (float)exp((double)z);  // CR fp32 exp
      const float u = __shfl(u40, q, 64);
      if (u < pacc) {
        if (lane == p) scur = bidx;                     // accept jump
        // Re-evaluate this position's FUTURE steps under the new state.
        const unsigned long long fut =
            (((1ull << (p * 5 + 5)) - 1) & ~((1ull << (q + 1)) - 1));
        const float pnew = pthr[bidx];                  // scalar (bidx uniform)
        const unsigned long long nb = __ballot(u40 < pnew) & fut;
        mask = (mask & ~fut) | nb;
      }
    }
    if (lane < PPW) x_out[base + lane] = scur;
  }
}

extern "C" void kernel_launch(void* const* d_in, const int* in_sizes, int n_in,
                              void* d_out, int out_size, void* d_ws, size_t ws_size,
                              hipStream_t stream) {
  const int*   x   = (const int*)d_in[0];
  const float* emb = (const float*)d_in[1];
  const float* W1  = (const float*)d_in[2];
  const float* b1  = (const float*)d_in[3];
  const float* W2  = (const float*)d_in[4];
  const float* b2  = (const float*)d_in[5];
  float* I    = (float*)d_ws;                        // 1 MiB
  float* pthr = (float*)d_ws + VOCAB * VOCAB;        // +2 KiB
  int* out = (int*)d_out;

  // Host-side key derivation (partitionable scheme):
  //   key(42) = (0,42); split -> S_t = tf(key,(0,t)); (k1,k2) = tf(S_t,(0,j))
  Keys K;
  for (int t = 0; t < STEPS; ++t) {
    uint32_t Sa, Sb;
    tf2x32(0u, 42u, 0u, (uint32_t)t, Sa, Sb);
    tf2x32(Sa, Sb, 0u, 0u, K.k1a[t], K.k1b[t]);
    tf2x32(Sa, Sb, 0u, 1u, K.k2a[t], K.k2b[t]);
  }

  build_table<<<VOCAB, 512, 0, stream>>>(emb, W1, b1, W2, b2, I, pthr);
  markov_kernel<<<NWAVE / 4, 256, 0, stream>>>(x, I, pthr, out, K);
}

// Round 8
// 109.370 us; speedup vs baseline: 1.0752x; 1.0752x over previous
//
#include <hip/hip_runtime.h>
#include <stdint.h>

// DiscreteMarkovDynamics: 5-step Markov jump sim, B=32, L=4096, V=512.
// R1: table precompute + wave-per-position categorical -> 1024 us.
// R2: provable-reject skip (u >= pthr[s] => categorical dead code) -> 250 us.
// R3: split/parallel builds, LDS pthr, PPW=8 -> 125 us.
// R4: fused wide build; ballot candidate scan -> 121 us (markov 52).
// R5: zoned work-steal REGRESSED (16 counters in ONE cacheline -> all atomics
//     serialized cross-XCD) -> 293 us. Reverted.
// R6: 2-wave blocks + ILP categorical -> 116 us (markov 45).
// R7: static 2 chunks/wave REGRESSED markov to 53 (no backfill -> Poisson-max
//     tail). Accounting across R3-R7: total = ~70 us harness reset train
//     + kernels. Controllable part: markov (ideal ~17-20 us issue-bound).
// R8: 2048x256 blocks (exact residency, one ramp), 8 chunks/block pulled by
//     the block's 4 waves from an LDS atomic counter: dynamic balancing with
//     ZERO global atomics (R5's failure mode structurally impossible).

#define VOCAB  512
#define EMB    256
#define HID    64
#define NPOS   (32 * 4096)   // B*L = 131072
#define STEPS  5
#define PPW    8             // positions per chunk; PPW*STEPS=40 <= 64 lanes
#define CHUNKS (NPOS / PPW)  // 16384
#define MBLK   2048          // markov blocks; 8 chunks per block
#define CPB    (CHUNKS / MBLK)  // 8

// Exact mirror of jax._src.prng.threefry2x32 (20 rounds).
__host__ __device__ __forceinline__ void tf2x32(uint32_t k0, uint32_t k1,
                                                uint32_t x0, uint32_t x1,
                                                uint32_t& o0, uint32_t& o1) {
  uint32_t ks2 = k0 ^ k1 ^ 0x1BD11BDAu;
  x0 += k0; x1 += k1;
#define TFR(r) { x0 += x1; x1 = (x1 << (r)) | (x1 >> (32 - (r))); x1 ^= x0; }
  TFR(13) TFR(15) TFR(26) TFR(6)
  x0 += k1;  x1 += ks2 + 1u;
  TFR(17) TFR(29) TFR(16) TFR(24)
  x0 += ks2; x1 += k0 + 2u;
  TFR(13) TFR(15) TFR(26) TFR(6)
  x0 += k0;  x1 += k1 + 3u;
  TFR(17) TFR(29) TFR(16) TFR(24)
  x0 += k1;  x1 += ks2 + 4u;
  TFR(13) TFR(15) TFR(26) TFR(6)
  x0 += ks2; x1 += k0 + 5u;
#undef TFR
  o0 = x0; o1 = x1;
}

struct Keys {
  uint32_t k1a[STEPS], k1b[STEPS];  // categorical (gumbel) keys per step
  uint32_t k2a[STEPS], k2b[STEPS];  // accept-uniform keys per step
};

// Fused table build (R7's load-batched version; in-graph it is a few us --
// the 150 us rocprof numbers in R2 were for the old 2-wave/CU chain version).
__global__ __launch_bounds__(512)
void build_table(const float* __restrict__ emb,
                 const float* __restrict__ W1,
                 const float* __restrict__ b1,
                 const float* __restrict__ W2,
                 const float* __restrict__ b2,
                 float* __restrict__ I,
                 float* __restrict__ pthr) {
  const int s   = blockIdx.x;
  const int tid = threadIdx.x;
  __shared__ double part[8][HID];
  __shared__ double hd[HID];
  __shared__ float  redmax[8];

  const int hid = tid & (HID - 1);
  const int kq  = tid >> 6;               // 0..7, k = kq + 8*i
  const float* e = emb + s * EMB;
  double acc = 0.0;
#pragma unroll
  for (int ib = 0; ib < 32; ib += 16) {   // two 16-wide batches
    float ev[16], wv[16];
#pragma unroll
    for (int i = 0; i < 16; ++i) {        // 32 loads issued together
      const int k = kq + 8 * (ib + i);
      ev[i] = e[k];
      wv[i] = W1[k * HID + hid];
    }
#pragma unroll
    for (int i = 0; i < 16; ++i)          // same order as R4's k-loop
      acc += (double)ev[i] * (double)wv[i];
  }
  part[kq][hid] = acc;
  __syncthreads();
  if (kq == 0) {
    const double a = ((part[0][hid] + part[1][hid]) + (part[2][hid] + part[3][hid]))
                   + ((part[4][hid] + part[5][hid]) + (part[6][hid] + part[7][hid]));
    const float m = (float)a + b1[hid];
    hd[hid] = (double)(m > 0.0f ? m : 0.0f);   // relu
  }
  __syncthreads();

  double acc2 = 0.0;
#pragma unroll
  for (int kb = 0; kb < HID; kb += 16) {  // four 16-wide batches
    float wv[16];
#pragma unroll
    for (int i = 0; i < 16; ++i)
      wv[i] = W2[(kb + i) * VOCAB + tid]; // coalesced, 16 in flight
#pragma unroll
    for (int i = 0; i < 16; ++i)          // same serial order as before
      acc2 += hd[kb + i] * (double)wv[i];
  }
  const float val = (float)acc2 + b2[tid];
  I[s * VOCAB + tid] = val;

  float lmax = val;                        // max is order-insensitive
  for (int off = 32; off > 0; off >>= 1)
    lmax = fmaxf(lmax, __shfl_xor(lmax, off, 64));
  if ((tid & 63) == 0) redmax[tid >> 6] = lmax;
  __syncthreads();
  if (tid == 0) {
    float m = redmax[0];
#pragma unroll
    for (int i = 1; i < 8; ++i) m = fmaxf(m, redmax[i]);
    const float z = (-m) * 0.01f;          // same chain as accept path
    pthr[s] = 1.0f - (float)exp((double)z);// monotone => safe reject bound
  }
}

// Markov kernel: 2048 blocks x 256 = exact full residency (zero churn, one
// ramp). Each block owns 8 chunks; its 4 waves pull them from an LDS atomic
// counter (block-local dynamic balancing, zero global atomics).
__global__ __launch_bounds__(256)
void markov_kernel(const int* __restrict__ x_in,
                   const float* __restrict__ I,
                   const float* __restrict__ pthr,
                   int* __restrict__ x_out,
                   Keys K) {
  __shared__ int next_chunk;
  if (threadIdx.x == 0) next_chunk = 0;
  __syncthreads();

  const int lane = threadIdx.x & 63;
  const int qp = lane / 5;                 // lane q -> (position, step)
  const int qt = lane - qp * 5;
  const float TINYF = 1.17549435e-38f;

  for (;;) {
    int c = 0;
    if (lane == 0) c = atomicAdd(&next_chunk, 1);   // LDS atomic: cheap
    c = __shfl(c, 0, 64);                            // wave-uniform
    if (c >= CPB) break;
    const int base = (blockIdx.x * CPB + c) * PPW;

    // States (lanes 0..7), then per-position pthr, shfl'd to the test lanes.
    int scur = (lane < PPW) ? x_in[base + lane] : 0;
    const float pv = (lane < PPW) ? pthr[scur] : 0.0f;

    // Accept uniforms: lane q < 40 holds u for (p=q/5, t=q%5).
    float u40 = 0.0f;
    if (lane < PPW * STEPS) {
      uint32_t w0, w1;
      tf2x32(K.k2a[qt], K.k2b[qt], 0u, (uint32_t)(base + qp), w0, w1);
      u40 = __uint_as_float((((w0 ^ w1) >> 9) | 0x3f800000u)) - 1.0f;
    }

    // Candidate mask: u_q < pthr[s_p] (state fixed unless an accept occurs).
    const float pq = __shfl(pv, qp, 64);
    const bool cand = (lane < PPW * STEPS) && (u40 < pq);
    unsigned long long mask = __ballot(cand);

    while (mask) {
      const int q = (int)__builtin_ctzll(mask);   // wave-uniform
      mask &= mask - 1;
      const int p = q / 5;
      const int t = q - p * 5;
      const int s = __builtin_amdgcn_readfirstlane(__shfl(scur, p, 64));

      // --- Full categorical (bit-identical math; ILP-batched) ---
      const float* row = I + s * VOCAB;
      float rv[8];
#pragma unroll
      for (int j = 0; j < 8; ++j)               // prefetch row values (L2)
        rv[j] = row[lane + (j << 6)];

      const uint32_t fbase = ((uint32_t)(base + p) << 9) + (uint32_t)lane;
      uint32_t bits[8];
#pragma unroll
      for (int j = 0; j < 8; ++j) {             // 8 independent threefry
        uint32_t w0, w1;
        tf2x32(K.k1a[t], K.k1b[t], 0u, fbase + ((uint32_t)j << 6), w0, w1);
        bits[j] = w0 ^ w1;
      }

      float best = -__builtin_inff();
      float rbest = 0.0f;                        // row value of the winner
      int bidx = 0;
#pragma unroll
      for (int j = 0; j < 8; ++j) {             // 8 independent gumbel chains
        float ufv = __uint_as_float((bits[j] >> 9) | 0x3f800000u) - 1.0f;
        if (ufv == 0.0f) ufv = TINYF;
        const float g = -logf(-logf(ufv));
        const int v = lane + (j << 6);
        if (v != s) {
          const float val = rv[j] + g;
          if (val > best) { best = val; bidx = v; rbest = rv[j]; }
        }
      }
      for (int off = 32; off > 0; off >>= 1) {
        const float ob = __shfl_xor(best, off, 64);
        const int   oi = __shfl_xor(bidx, off, 64);
        const float orv = __shfl_xor(rbest, off, 64);
        if (ob > best || (ob == best && oi < bidx)) {
          best = ob; bidx = oi; rbest = orv;
        }
      }
      bidx = __builtin_amdgcn_readfirstlane(bidx);
      const float rate = rbest;                 // == row[bidx], no L2 load
      const float z = (-rate) * 0.01f;
      const float pacc = 1.0f - (float)exp((double)z);  // CR fp32 exp
      const float u = __shfl(u40, q, 64);
      if (u < pacc) {
        if (lane == p) scur = bidx;                     // accept jump
        // Re-evaluate this position's FUTURE steps under the new state.
        const unsigned long long fut =
            (((1ull << (p * 5 + 5)) - 1) & ~((1ull << (q + 1)) - 1));
        const float pnew = pthr[bidx];                  // scalar (bidx uniform)
        const unsigned long long nb = __ballot(u40 < pnew) & fut;
        mask = (mask & ~fut) | nb;
      }
    }
    if (lane < PPW) x_out[base + lane] = scur;
  }
}

extern "C" void kernel_launch(void* const* d_in, const int* in_sizes, int n_in,
                              void* d_out, int out_size, void* d_ws, size_t ws_size,
                              hipStream_t stream) {
  const int*   x   = (const int*)d_in[0];
  const float* emb = (const float*)d_in[1];
  const float* W1  = (const float*)d_in[2];
  const float* b1  = (const float*)d_in[3];
  const float* W2  = (const float*)d_in[4];
  const float* b2  = (const float*)d_in[5];
  float* I    = (float*)d_ws;                        // 1 MiB
  float* pthr = (float*)d_ws + VOCAB * VOCAB;        // +2 KiB
  int* out = (int*)d_out;

  // Host-side key derivation (partitionable scheme):
  //   key(42) = (0,42); split -> S_t = tf(key,(0,t)); (k1,k2) = tf(S_t,(0,j))
  Keys K;
  for (int t = 0; t < STEPS; ++t) {
    uint32_t Sa, Sb;
    tf2x32(0u, 42u, 0u, (uint32_t)t, Sa, Sb);
    tf2x32(Sa, Sb, 0u, 0u, K.k1a[t], K.k1b[t]);
    tf2x32(Sa, Sb, 0u, 1u, K.k2a[t], K.k2b[t]);
  }

  build_table<<<VOCAB, 512, 0, stream>>>(emb, W1, b1, W2, b2, I, pthr);
  markov_kernel<<<MBLK, 256, 0, stream>>>(x, I, pthr, out, K);
}